// Round 6
// baseline (442.371 us; speedup 1.0000x reference)
//
#include <hip/hip_runtime.h>

#define DIM 1024
#define NQ 6

// R6: two-pass split, correctly implemented. Evidence: pure-write streams
// (harness fills) hit 6.5 TB/s at 10% occupancy; every fused variant with
// the 256 MiB read stream is pinned at ~4.65 TB/s, and 5 compute/sync
// theories (DS throughput, barrier count, barrier drain, cache eviction,
// ILP) are measured null. R3's split failed for implementation reasons:
// pass2 had a dependent unprefetched 128B L3 read per row (serial ~500cy
// chain), pass1 unknown occupancy. This version fixes both:
//  - pass1: read-stream kernel, 24 waves/CU (launch_bounds 256,6), nt x
//    loads, wave-private reduction, 32B qpart store/wave. No barriers.
//  - pass2: write-stream kernel, qpart row prefetched one iteration ahead
//    into registers (L3 latency hides under cos+FMA+store), nt out stores.
// Butterfly (verified R0): xor1->0xB1, xor2->0x4E, xor7->0x141(mirror),
// xor8->0x128(ror8); fold bits s1=(l^(l>>2))&1, s2=(l^(l>>1))&1,
// s3=(l>>2)&1, vperm=4s1+2s2+s3 (bijective on each 8-lane group).

typedef float v4f __attribute__((ext_vector_type(4)));

template <int CTRL>
__device__ __forceinline__ float dpp_mov(float x) {
    return __int_as_float(__builtin_amdgcn_update_dpp(
        0, __float_as_int(x), CTRL, 0xF, 0xF, true));
}

__device__ __forceinline__ float butterfly6(const float* p, int s1, int s2, int s3) {
    float r4[4];
#pragma unroll
    for (int i = 0; i < 4; ++i) {
        float send = s1 ? p[i] : p[i + 4];
        float keep = s1 ? p[i + 4] : p[i];
        r4[i] = keep + dpp_mov<0xB1>(send);   // xor1
    }
    float r2[2];
#pragma unroll
    for (int i = 0; i < 2; ++i) {
        float send = s2 ? r4[i] : r4[i + 2];
        float keep = s2 ? r4[i + 2] : r4[i];
        r2[i] = keep + dpp_mov<0x4E>(send);   // xor2
    }
    float send = s3 ? r2[0] : r2[1];
    float keep = s3 ? r2[1] : r2[0];
    float r1 = keep + dpp_mov<0x141>(send);   // xor7 row_half_mirror
    r1 += dpp_mov<0x128>(r1);                 // xor8 row_ror:8
    r1 += __shfl_xor(r1, 16, 64);
    r1 += __shfl_xor(r1, 32, 64);
    return r1;
}

// ---------------- Pass 1: x -> per-wave partial sums (read stream) ----------------
__global__ __launch_bounds__(256, 6) void ffq_pass1(
    const float* __restrict__ x,
    const float* __restrict__ w1,
    float* __restrict__ qpart,      // [n_rows][4 waves][8]
    int n_rows)
{
    const int t    = threadIdx.x;
    const int lane = t & 63;
    const int wave = t >> 6;
    const int d0   = t * 4;

    float w1f[NQ][4];
#pragma unroll
    for (int q = 0; q < NQ; ++q) {
        v4f v = *reinterpret_cast<const v4f*>(w1 + q * DIM + d0);
        w1f[q][0] = v.x; w1f[q][1] = v.y; w1f[q][2] = v.z; w1f[q][3] = v.w;
    }

    const int s1 = (lane ^ (lane >> 2)) & 1;
    const int s2 = (lane ^ (lane >> 1)) & 1;
    const int s3 = (lane >> 2) & 1;
    const int vperm = 4 * s1 + 2 * s2 + s3;

    const int stride = gridDim.x;
    int r = blockIdx.x;

    v4f xv = (v4f){0.f, 0.f, 0.f, 0.f};
    if (r < n_rows)
        xv = __builtin_nontemporal_load(
            reinterpret_cast<const v4f*>(x + (size_t)r * DIM + d0));

    while (r < n_rows) {
        const int rn = r + stride;
        v4f xn = (v4f){0.f, 0.f, 0.f, 0.f};
        if (rn < n_rows)
            xn = __builtin_nontemporal_load(
                reinterpret_cast<const v4f*>(x + (size_t)rn * DIM + d0));

        float p[8];
#pragma unroll
        for (int q = 0; q < NQ; ++q)
            p[q] = fmaf(xv.x, w1f[q][0],
                   fmaf(xv.y, w1f[q][1],
                   fmaf(xv.z, w1f[q][2], xv.w * w1f[q][3])));
        p[6] = 0.f; p[7] = 0.f;

        float r1 = butterfly6(p, s1, s2, s3);

        if (lane < 8)
            qpart[(size_t)r * 32 + wave * 8 + vperm] = r1;  // 32B/wave, L2-resident

        xv = xn;
        r = rn;
    }
}

// ---------------- Pass 2: partials -> cos -> out (write stream) ----------------
__global__ __launch_bounds__(256, 4) void ffq_pass2(
    const float* __restrict__ qpart,
    const float* __restrict__ b1,
    const float* __restrict__ theta,
    const float* __restrict__ w2,
    const float* __restrict__ b2,
    float* __restrict__ out,
    int n_rows)
{
    const int t  = threadIdx.x;
    const int d0 = t * 4;

    float w2f[4][NQ];  // w2f[i][q] = w2[(d0+i)*6 + q]
    {
        const v4f* wp = reinterpret_cast<const v4f*>(w2 + (size_t)d0 * NQ);
        float* flat = &w2f[0][0];
#pragma unroll
        for (int i = 0; i < 6; ++i) {
            v4f v = wp[i];
            flat[4 * i + 0] = v.x; flat[4 * i + 1] = v.y;
            flat[4 * i + 2] = v.z; flat[4 * i + 3] = v.w;
        }
    }
    const v4f b2v = *reinterpret_cast<const v4f*>(b2 + d0);
    float b1f[NQ], ctf[NQ];
#pragma unroll
    for (int q = 0; q < NQ; ++q) {
        b1f[q] = b1[q];
        ctf[q] = __cosf(theta[q]);
    }

    const int stride = gridDim.x;
    int r = blockIdx.x;

    // prefetched qpart row (8 x float4 = 128B, broadcast across threads)
    v4f qn[8];
#pragma unroll
    for (int i = 0; i < 8; ++i) qn[i] = (v4f){0.f, 0.f, 0.f, 0.f};
    if (r < n_rows) {
        const v4f* rp = reinterpret_cast<const v4f*>(qpart + (size_t)r * 32);
#pragma unroll
        for (int i = 0; i < 8; ++i) qn[i] = rp[i];
    }

    while (r < n_rows) {
        // consume prefetched row into sums (register ops only)
        v4f slo = (qn[0] + qn[2]) + (qn[4] + qn[6]);  // q0..q3
        v4f shi = (qn[1] + qn[3]) + (qn[5] + qn[7]);  // q4..q5

        // immediately issue next row's loads (reuse qn; L3 latency hides
        // under the cos+FMA+store below)
        const int rn = r + stride;
        if (rn < n_rows) {
            const v4f* rp = reinterpret_cast<const v4f*>(qpart + (size_t)rn * 32);
#pragma unroll
            for (int i = 0; i < 8; ++i) qn[i] = rp[i];
        }

        float qv[NQ];
        qv[0] = slo.x; qv[1] = slo.y; qv[2] = slo.z; qv[3] = slo.w;
        qv[4] = shi.x; qv[5] = shi.y;
#pragma unroll
        for (int q = 0; q < NQ; ++q)
            qv[q] = __cosf(qv[q] + b1f[q]) * ctf[q];

        v4f o = b2v;
#pragma unroll
        for (int q = 0; q < NQ; ++q) {
            o.x = fmaf(qv[q], w2f[0][q], o.x);
            o.y = fmaf(qv[q], w2f[1][q], o.y);
            o.z = fmaf(qv[q], w2f[2][q], o.z);
            o.w = fmaf(qv[q], w2f[3][q], o.w);
        }
        o.x = fmaxf(o.x, 0.f); o.y = fmaxf(o.y, 0.f);
        o.z = fmaxf(o.z, 0.f); o.w = fmaxf(o.w, 0.f);

        __builtin_nontemporal_store(
            o, reinterpret_cast<v4f*>(out + (size_t)r * DIM + d0));

        r = rn;
    }
}

// ---------------- Fallback: fused single kernel (R5 version) ----------------
__global__ __launch_bounds__(256, 4) void ffq_fused(
    const float* __restrict__ x,
    const float* __restrict__ w1,
    const float* __restrict__ b1,
    const float* __restrict__ theta,
    const float* __restrict__ w2,
    const float* __restrict__ b2,
    float* __restrict__ out,
    int n_rows)
{
    const int t    = threadIdx.x;
    const int lane = t & 63;
    const int wave = t >> 6;
    const int d0   = t * 4;

    float w1f[NQ][4];
#pragma unroll
    for (int q = 0; q < NQ; ++q) {
        v4f v = *reinterpret_cast<const v4f*>(w1 + q * DIM + d0);
        w1f[q][0] = v.x; w1f[q][1] = v.y; w1f[q][2] = v.z; w1f[q][3] = v.w;
    }
    float w2f[4][NQ];
    {
        const v4f* wp = reinterpret_cast<const v4f*>(w2 + (size_t)d0 * NQ);
        float* flat = &w2f[0][0];
#pragma unroll
        for (int i = 0; i < 6; ++i) {
            v4f v = wp[i];
            flat[4 * i + 0] = v.x; flat[4 * i + 1] = v.y;
            flat[4 * i + 2] = v.z; flat[4 * i + 3] = v.w;
        }
    }
    const v4f b2v = *reinterpret_cast<const v4f*>(b2 + d0);
    float b1f[NQ], ctf[NQ];
#pragma unroll
    for (int q = 0; q < NQ; ++q) {
        b1f[q] = b1[q];
        ctf[q] = __cosf(theta[q]);
    }

    const int s1 = (lane ^ (lane >> 2)) & 1;
    const int s2 = (lane ^ (lane >> 1)) & 1;
    const int s3 = (lane >> 2) & 1;
    const int vperm = 4 * s1 + 2 * s2 + s3;

    __shared__ __align__(16) float red[2][4][8];

    const int stride = gridDim.x;
    int r = blockIdx.x;
    int par = 0;

    v4f xv = (v4f){0.f, 0.f, 0.f, 0.f};
    if (r < n_rows)
        xv = __builtin_nontemporal_load(
            reinterpret_cast<const v4f*>(x + (size_t)r * DIM + d0));

    while (r < n_rows) {
        const int rn = r + stride;
        v4f xn = (v4f){0.f, 0.f, 0.f, 0.f};
        if (rn < n_rows)
            xn = __builtin_nontemporal_load(
                reinterpret_cast<const v4f*>(x + (size_t)rn * DIM + d0));

        float p[8];
#pragma unroll
        for (int q = 0; q < NQ; ++q)
            p[q] = fmaf(xv.x, w1f[q][0],
                   fmaf(xv.y, w1f[q][1],
                   fmaf(xv.z, w1f[q][2], xv.w * w1f[q][3])));
        p[6] = 0.f; p[7] = 0.f;

        float r1 = butterfly6(p, s1, s2, s3);

        if (lane < 8) red[par][wave][vperm] = r1;
        __syncthreads();

        const v4f* rp = reinterpret_cast<const v4f*>(&red[par][0][0]);
        v4f slo = (rp[0] + rp[2]) + (rp[4] + rp[6]);
        v4f shi = (rp[1] + rp[3]) + (rp[5] + rp[7]);
        float qv[NQ];
        qv[0] = slo.x; qv[1] = slo.y; qv[2] = slo.z; qv[3] = slo.w;
        qv[4] = shi.x; qv[5] = shi.y;
#pragma unroll
        for (int q = 0; q < NQ; ++q)
            qv[q] = __cosf(qv[q] + b1f[q]) * ctf[q];

        v4f o = b2v;
#pragma unroll
        for (int q = 0; q < NQ; ++q) {
            o.x = fmaf(qv[q], w2f[0][q], o.x);
            o.y = fmaf(qv[q], w2f[1][q], o.y);
            o.z = fmaf(qv[q], w2f[2][q], o.z);
            o.w = fmaf(qv[q], w2f[3][q], o.w);
        }
        o.x = fmaxf(o.x, 0.f); o.y = fmaxf(o.y, 0.f);
        o.z = fmaxf(o.z, 0.f); o.w = fmaxf(o.w, 0.f);

        __builtin_nontemporal_store(
            o, reinterpret_cast<v4f*>(out + (size_t)r * DIM + d0));

        xv = xn;
        r = rn;
        par ^= 1;
    }
}

extern "C" void kernel_launch(void* const* d_in, const int* in_sizes, int n_in,
                              void* d_out, int out_size, void* d_ws, size_t ws_size,
                              hipStream_t stream) {
    const float* x     = (const float*)d_in[0];
    const float* w1    = (const float*)d_in[1];
    const float* b1    = (const float*)d_in[2];
    const float* theta = (const float*)d_in[3];
    const float* w2    = (const float*)d_in[4];
    const float* b2    = (const float*)d_in[5];
    float* out = (float*)d_out;

    const int n_rows = in_sizes[0] / DIM;  // B*S = 65536
    const size_t need = (size_t)n_rows * 32 * sizeof(float);  // 8.4 MB

    if (d_ws != nullptr && ws_size >= need) {
        float* qpart = (float*)d_ws;
        ffq_pass1<<<2048, 256, 0, stream>>>(x, w1, qpart, n_rows);
        ffq_pass2<<<2048, 256, 0, stream>>>(qpart, b1, theta, w2, b2, out, n_rows);
    } else {
        ffq_fused<<<1024, 256, 0, stream>>>(x, w1, b1, theta, w2, b2, out, n_rows);
    }
}